// Round 6
// baseline (276.429 us; speedup 1.0000x reference)
//
#include <hip/hip_runtime.h>

// PhaseCoherenceLoss: scalar reduction over (B=2048, T=8192, 3) fp32 logits.
// For pair (t,t+1): pt=argmax[t], pt1=argmax[t+1]; if illegal[pt][pt1],
// accumulate (max logit at t+1)^2 and count. out = count>0 ? 10*loss/count : 0.
// Illegal codes pt*3+pt1 in {2,3,6,7} -> bitmask 0xCC.
//
// R1: same-address atomics serialized (392us @ 3% BW) -> two-stage reduction.
// R3/R5: ~70us, 2.8 TB/s, structure-independent -> NOT latency-bound.
//   Diagnosis: 3x float4 per 48B chunk at 48-B lane stride = each instruction
//   scatters 64 lanes over the same ~48 cache lines -> 3x line-request
//   amplification in L1/TA.
// R6: one global_load_dwordx3 per TIMESTEP at 12-B lane stride — wave covers
//   768 contiguous bytes per instruction, 1x request rate, no redistribution.
//   Successor argmax from lane+1 via ONE packed shfl (argidx in 2 low mantissa
//   bits of the max value; 2^-21 rel err, negligible). Lane 63: masked
//   fallback dwordx3 batched with the main loads (latency hidden, +1.5% traffic).

#define TLEN      8192
#define TMASK     8191u
#define NTHREADS  256
#define KCH       8
#define NBLK      8192          // 2048*8192 timesteps = NBLK*NTHREADS*KCH exactly

struct alignas(4) F3 { float a, b, c; };

__device__ __forceinline__ F3 load_f3(const float* __restrict__ p) {
    F3 v;
    __builtin_memcpy(&v, p, sizeof(F3));   // 12B, align 4 -> global_load_dwordx3
    return v;
}

// pack: (bits(max) & ~3) | argidx  — strict > keeps first-max (argmax tie-break)
__device__ __forceinline__ int argmax3_pack(F3 v) {
    float bm = v.a; int bi = 0;
    if (v.b > bm) { bm = v.b; bi = 1; }
    if (v.c > bm) { bm = v.c; bi = 2; }
    return (__float_as_int(bm) & ~3) | bi;
}

__global__ __launch_bounds__(NTHREADS) void pcl_main(const float* __restrict__ x,
                                                     float* __restrict__ part_loss,
                                                     unsigned int* __restrict__ part_cnt,
                                                     unsigned int total) {
    const unsigned int gsz = NBLK * NTHREADS;
    const unsigned int gid = blockIdx.x * NTHREADS + threadIdx.x;
    const int lane = threadIdx.x & 63;

    // Batch all loads first: 8 own + 8 masked lane-63 fallbacks, all independent.
    F3 own[KCH];
    #pragma unroll
    for (int j = 0; j < KCH; ++j) {
        unsigned int c = gid + (unsigned int)j * gsz;
        own[j] = load_f3(x + (size_t)3 * c);
    }

    F3 nbv[KCH];
    if (lane == 63) {
        #pragma unroll
        for (int j = 0; j < KCH; ++j) {
            unsigned int s = gid + (unsigned int)j * gsz + 1u;
            if (s >= total) s = total - 1u;      // clamp: value unused at row end
            nbv[j] = load_f3(x + (size_t)3 * s);
        }
    }

    int pk[KCH];
    #pragma unroll
    for (int j = 0; j < KCH; ++j) pk[j] = argmax3_pack(own[j]);

    int fb[KCH] = {};
    if (lane == 63) {
        #pragma unroll
        for (int j = 0; j < KCH; ++j) fb[j] = argmax3_pack(nbv[j]);
    }

    float loss = 0.0f;
    unsigned int cnt = 0;
    #pragma unroll
    for (int j = 0; j < KCH; ++j) {
        unsigned int c = gid + (unsigned int)j * gsz;
        int npk = __shfl_down(pk[j], 1, 64);     // lane+1's (max,argmax)
        if (lane == 63) npk = fb[j];
        if ((c & TMASK) != TMASK) {              // skip row-last timestep
            int code = (pk[j] & 3) * 3 + (npk & 3);
            if ((0xCC >> code) & 1) {
                float nmx = __int_as_float(npk & ~3);
                loss = fmaf(nmx, nmx, loss);
                cnt++;
            }
        }
    }

    // wave-64 reduce
    #pragma unroll
    for (int off = 32; off > 0; off >>= 1) {
        loss += __shfl_down(loss, off, 64);
        cnt  += __shfl_down(cnt,  off, 64);
    }

    __shared__ float        sl[4];
    __shared__ unsigned int sc[4];
    int wid = threadIdx.x >> 6;
    if (lane == 0) { sl[wid] = loss; sc[wid] = cnt; }
    __syncthreads();

    if (threadIdx.x == 0) {
        part_loss[blockIdx.x] = sl[0] + sl[1] + sl[2] + sl[3];
        part_cnt[blockIdx.x]  = sc[0] + sc[1] + sc[2] + sc[3];
    }
}

__global__ __launch_bounds__(NTHREADS) void pcl_final(const float* __restrict__ part_loss,
                                                      const unsigned int* __restrict__ part_cnt,
                                                      float* __restrict__ out, int npart) {
    double L = 0.0;
    unsigned int C = 0;
    for (int i = threadIdx.x; i < npart; i += NTHREADS) {
        L += (double)part_loss[i];
        C += part_cnt[i];
    }
    #pragma unroll
    for (int off = 32; off > 0; off >>= 1) {
        L += __shfl_down(L, off, 64);
        C += __shfl_down(C, off, 64);
    }
    __shared__ double       sl[4];
    __shared__ unsigned int sc[4];
    int lane = threadIdx.x & 63;
    int wid  = threadIdx.x >> 6;
    if (lane == 0) { sl[wid] = L; sc[wid] = C; }
    __syncthreads();
    if (threadIdx.x == 0) {
        double       Lt = sl[0] + sl[1] + sl[2] + sl[3];
        unsigned int Ct = sc[0] + sc[1] + sc[2] + sc[3];
        out[0] = (Ct > 0u) ? (float)(10.0 * Lt / (double)Ct) : 0.0f;
    }
}

extern "C" void kernel_launch(void* const* d_in, const int* in_sizes, int n_in,
                              void* d_out, int out_size, void* d_ws, size_t ws_size,
                              hipStream_t stream) {
    const float* x = (const float*)d_in[0];
    const unsigned int total = (unsigned int)(in_sizes[0] / 3);   // timesteps = B*T

    // total = 2048*8192 = NBLK*NTHREADS*KCH -> every thread owns exactly KCH
    // timesteps, no bounds checks, all shfl lanes active.
    float*        part_loss = (float*)d_ws;
    unsigned int* part_cnt  = (unsigned int*)((char*)d_ws + (size_t)NBLK * sizeof(float));

    // All partial slots written unconditionally each call -> no memset needed
    // despite the 0xAA ws re-poison.
    pcl_main<<<NBLK, NTHREADS, 0, stream>>>(x, part_loss, part_cnt, total);
    pcl_final<<<1, NTHREADS, 0, stream>>>(part_loss, part_cnt, (float*)d_out, NBLK);
}

// Round 7
// 274.698 us; speedup vs baseline: 1.0063x; 1.0063x over previous
//
#include <hip/hip_runtime.h>

// PhaseCoherenceLoss: scalar reduction over (B, T=8192, 3) fp32 logits.
// For pair (t,t+1): pt=argmax[t], pt1=argmax[t+1]; if illegal[pt][pt1],
// accumulate (max logit at t+1)^2 and count. out = count>0 ? 10*loss/count : 0.
// Illegal codes pt*3+pt1 in {2,3,6,7} -> bitmask 0xCC.
//
// R1: same-address atomics serialized (392us @3%BW) -> two-stage reduction.
// R3/R5/R6: three different load structures all ~75us (2.7 TB/s) -> neither
//   coalescing-shape nor latency bound. Common factor: each wave's successive
//   tiles stride ~25MB -> thousands of interleaved DRAM streams chip-wide.
// R7: block-contiguous slabs. Block b owns timesteps [b*2048, (b+1)*2048):
//   one contiguous 24KB sweep per block, blocks in order -> monotonic
//   chip-wide sweep (same shape as the 6.8 TB/s harness fill).
//   Successor argmax: lane+1 shfl; wave/block boundary via tiny LDS table;
//   one extra 12B load per block (tid 255) for the cross-slab pair.

#define NTHREADS  256
#define SLAB      2048          // timesteps per block (24 KB)
#define JITER     8             // SLAB / NTHREADS
#define TLEN      8192          // timesteps per row; 4 slabs per row

struct alignas(4) F3 { float a, b, c; };

__device__ __forceinline__ F3 load_f3(const float* __restrict__ p) {
    F3 v;
    __builtin_memcpy(&v, p, sizeof(F3));   // 12B -> global_load_dwordx3
    return v;
}

// pack (bits(max) & ~3) | argidx — strict > keeps first-max tie-break.
// 2 low mantissa bits dropped: 2^-21 rel err on loss, vs 0.255 abs threshold.
__device__ __forceinline__ int argmax3_pack(F3 v) {
    float bm = v.a; int bi = 0;
    if (v.b > bm) { bm = v.b; bi = 1; }
    if (v.c > bm) { bm = v.c; bi = 2; }
    return (__float_as_int(bm) & ~3) | bi;
}

__global__ __launch_bounds__(NTHREADS) void pcl_main(const float* __restrict__ x,
                                                     float* __restrict__ part_loss,
                                                     unsigned int* __restrict__ part_cnt) {
    const int tid  = threadIdx.x;
    const int lane = tid & 63;
    const int wv   = tid >> 6;
    const float* xb = x + (size_t)blockIdx.x * SLAB * 3;

    // contiguous slab: thread reads timestep (tid + j*256); wave = 768B contig
    F3 own[JITER];
    #pragma unroll
    for (int j = 0; j < JITER; ++j)
        own[j] = load_f3(xb + (size_t)3 * (tid + j * NTHREADS));

    // cross-slab successor (timestep slab_base+2048), unless row end
    const bool has_next = ((blockIdx.x & 3u) != 3u);    // TLEN/SLAB = 4 slabs/row
    F3 nextv = own[0];
    if (tid == NTHREADS - 1 && has_next)
        nextv = load_f3(xb + (size_t)3 * SLAB);

    int pk[JITER];
    #pragma unroll
    for (int j = 0; j < JITER; ++j) pk[j] = argmax3_pack(own[j]);

    // wave-boundary successor table: lane-0 packs of each wave
    __shared__ int sm[4][JITER];
    if (lane == 0) {
        #pragma unroll
        for (int j = 0; j < JITER; ++j) sm[wv][j] = pk[j];
    }
    __syncthreads();

    float loss = 0.0f;
    unsigned int cnt = 0;
    #pragma unroll
    for (int j = 0; j < JITER; ++j) {
        int npk = __shfl_down(pk[j], 1, 64);            // successor = tid+1, same j
        if (lane == 63) {
            if (wv < 3)              npk = sm[wv + 1][j];        // next wave, same j
            else if (j < JITER - 1)  npk = sm[0][j + 1];         // tid 255 -> tid 0, j+1
            else                     npk = argmax3_pack(nextv);  // cross-slab
        }
        bool valid = !(wv == 3 && lane == 63 && j == JITER - 1 && !has_next);
        if (valid) {
            int code = (pk[j] & 3) * 3 + (npk & 3);
            if ((0xCC >> code) & 1) {
                float nmx = __int_as_float(npk & ~3);
                loss = fmaf(nmx, nmx, loss);
                cnt++;
            }
        }
    }

    // wave-64 reduce
    #pragma unroll
    for (int off = 32; off > 0; off >>= 1) {
        loss += __shfl_down(loss, off, 64);
        cnt  += __shfl_down(cnt,  off, 64);
    }

    __shared__ float        sl[4];
    __shared__ unsigned int sc[4];
    if (lane == 0) { sl[wv] = loss; sc[wv] = cnt; }
    __syncthreads();

    if (tid == 0) {
        part_loss[blockIdx.x] = sl[0] + sl[1] + sl[2] + sl[3];
        part_cnt[blockIdx.x]  = sc[0] + sc[1] + sc[2] + sc[3];
    }
}

__global__ __launch_bounds__(NTHREADS) void pcl_final(const float* __restrict__ part_loss,
                                                      const unsigned int* __restrict__ part_cnt,
                                                      float* __restrict__ out, int npart) {
    double L = 0.0;
    unsigned int C = 0;
    for (int i = threadIdx.x; i < npart; i += NTHREADS) {
        L += (double)part_loss[i];
        C += part_cnt[i];
    }
    #pragma unroll
    for (int off = 32; off > 0; off >>= 1) {
        L += __shfl_down(L, off, 64);
        C += __shfl_down(C, off, 64);
    }
    __shared__ double       sl[4];
    __shared__ unsigned int sc[4];
    int lane = threadIdx.x & 63;
    int wid  = threadIdx.x >> 6;
    if (lane == 0) { sl[wid] = L; sc[wid] = C; }
    __syncthreads();
    if (threadIdx.x == 0) {
        double       Lt = sl[0] + sl[1] + sl[2] + sl[3];
        unsigned int Ct = sc[0] + sc[1] + sc[2] + sc[3];
        out[0] = (Ct > 0u) ? (float)(10.0 * Lt / (double)Ct) : 0.0f;
    }
}

extern "C" void kernel_launch(void* const* d_in, const int* in_sizes, int n_in,
                              void* d_out, int out_size, void* d_ws, size_t ws_size,
                              hipStream_t stream) {
    const float* x = (const float*)d_in[0];
    const int B = in_sizes[0] / (3 * TLEN);
    const int grid = B * (TLEN / SLAB);                 // 8192 for B=2048

    float*        part_loss = (float*)d_ws;
    unsigned int* part_cnt  = (unsigned int*)((char*)d_ws + (size_t)grid * sizeof(float));

    // All partial slots written unconditionally each call -> no memset needed
    // despite the 0xAA ws re-poison.
    pcl_main<<<grid, NTHREADS, 0, stream>>>(x, part_loss, part_cnt);
    pcl_final<<<1, NTHREADS, 0, stream>>>(part_loss, part_cnt, (float*)d_out, grid);
}